// Round 1
// 412.586 us; speedup vs baseline: 1.1907x; 1.1907x over previous
//
#include <hip/hip_runtime.h>

// network_5299989643808: per-(z,zp) tiny MLP over B observations.
// B=2048, Z=64, IDIM=2, HDIM=4, NOPT=4. f32 in / f32 out.
// Outputs concat flat: pi [B,Z,Z,4], log_pi [B,Z,Z,4], xi [B,Z,Z,4].
//
// R1: thread = one (z,zp) pair x BCHUNK=16 batch rows.
//   - weights (88 floats) hoisted to registers, amortized 16x
//     (kills 2.95 GB of repeated L1/L2 weight traffic + addr math)
//   - libm tanhf/expf/logf/fdiv replaced with v_exp2/v_log/v_rcp HW approx
//     (<=2 ulp; error << the 0.0078 absmax already tolerated)
// Stores remain float4, lane=zp => fully coalesced per wave.

#define ZD 64
#define BD 2048
#define NPAIR (ZD * ZD)   // 4096
#define BCHUNK 16

#define LOG2E 1.4426950408889634f
#define LN2   0.6931471805599453f

__device__ __forceinline__ void ld4(const float* __restrict__ p, float* d) {
    float4 v = *reinterpret_cast<const float4*>(p);
    d[0] = v.x; d[1] = v.y; d[2] = v.z; d[3] = v.w;
}

__device__ __forceinline__ float fast_exp(float x) {
    return __builtin_amdgcn_exp2f(x * LOG2E);
}

__device__ __forceinline__ float fast_tanh(float x) {
    // tanh(x) = (e^2x - 1) / (e^2x + 1); clamp so exp2 can't overflow (tanh(9)=1-2e-8)
    float y = fminf(fmaxf(x, -9.0f), 9.0f);
    float t = __builtin_amdgcn_exp2f(y * (2.0f * LOG2E));
    return (t - 1.0f) * __builtin_amdgcn_rcpf(t + 1.0f);
}

__device__ __forceinline__ void layernorm4(float* h, const float* g, const float* be) {
    float m = (h[0] + h[1] + h[2] + h[3]) * 0.25f;
    float d0 = h[0] - m, d1 = h[1] - m, d2 = h[2] - m, d3 = h[3] - m;
    float v = (d0 * d0 + d1 * d1 + d2 * d2 + d3 * d3) * 0.25f;
    float rs = rsqrtf(v + 1e-5f);
    h[0] = d0 * rs * g[0] + be[0];
    h[1] = d1 * rs * g[1] + be[1];
    h[2] = d2 * rs * g[2] + be[2];
    h[3] = d3 * rs * g[3] + be[3];
}

__global__ __launch_bounds__(256) void net_kernel(
    const float* __restrict__ nt,
    const float* __restrict__ W1,  const float* __restrict__ b1,
    const float* __restrict__ g1,  const float* __restrict__ be1,
    const float* __restrict__ W2,  const float* __restrict__ b2,
    const float* __restrict__ g2,  const float* __restrict__ be2,
    const float* __restrict__ Wpi, const float* __restrict__ bpi,
    const float* __restrict__ Wxi, const float* __restrict__ bxi,
    float* __restrict__ out)
{
    const int t  = blockIdx.x * 256 + threadIdx.x;   // 0 .. NPAIR*(BD/BCHUNK)-1
    const int p  = t & (NPAIR - 1);                  // (z,zp) pair; lane = zp
    const int zp = p & 63;
    const int z  = p >> 6;
    const int b0 = (t >> 12) * BCHUNK;               // this thread's batch slice

    // ---- per-pair weights -> registers, once per BCHUNK outputs ----
    float w1a[4], w1b[4], b1v[4], g1v[4], e1v[4];
    ld4(W1 + p * 8,     w1a);     // W1[z,zp,0,:]
    ld4(W1 + p * 8 + 4, w1b);     // W1[z,zp,1,:]
    ld4(b1  + p * 4, b1v);
    ld4(g1  + p * 4, g1v);
    ld4(be1 + p * 4, e1v);

    float w2v[16], b2v[4], g2v[4], e2v[4];
    #pragma unroll
    for (int i = 0; i < 4; ++i) ld4(W2 + p * 16 + i * 4, w2v + i * 4);
    ld4(b2  + p * 4, b2v);
    ld4(g2  + p * 4, g2v);
    ld4(be2 + p * 4, e2v);

    float wpv[16], bpv[4], wxv[16], bxv[4];
    #pragma unroll
    for (int i = 0; i < 4; ++i) {
        ld4(Wpi + p * 16 + i * 4, wpv + i * 4);
        ld4(Wxi + p * 16 + i * 4, wxv + i * 4);
    }
    ld4(bpi + p * 4, bpv);
    ld4(bxi + p * 4, bxv);

    const size_t OFF = (size_t)BD * NPAIR * 4;

    #pragma unroll 2
    for (int bi = 0; bi < BCHUNK; ++bi) {
        const int b = b0 + bi;
        const float x0 = nt[b * ZD + z];    // wave-uniform (whole wave shares z)
        const float x1 = nt[b * ZD + zp];   // coalesced across lanes

        // ---- layer 1: 2 -> 4, tanh, LN ----
        float h[4];
        #pragma unroll
        for (int i = 0; i < 4; ++i)
            h[i] = fast_tanh(fmaf(x0, w1a[i], fmaf(x1, w1b[i], b1v[i])));
        layernorm4(h, g1v, e1v);

        // ---- layer 2: 4 -> 4, tanh, LN ----
        float h2[4];
        #pragma unroll
        for (int k = 0; k < 4; ++k) {
            float a = b2v[k];
            #pragma unroll
            for (int i = 0; i < 4; ++i) a = fmaf(h[i], w2v[i * 4 + k], a);
            h2[k] = fast_tanh(a);
        }
        layernorm4(h2, g2v, e2v);

        // ---- heads ----
        float l[4], q[4];
        #pragma unroll
        for (int o = 0; o < 4; ++o) { l[o] = bpv[o]; q[o] = bxv[o]; }
        #pragma unroll
        for (int k = 0; k < 4; ++k) {
            #pragma unroll
            for (int o = 0; o < 4; ++o) {
                l[o] = fmaf(h2[k], wpv[k * 4 + o], l[o]);
                q[o] = fmaf(h2[k], wxv[k * 4 + o], q[o]);
            }
        }

        // ---- log-softmax / pi / sigmoid ----
        float mx = fmaxf(fmaxf(l[0], l[1]), fmaxf(l[2], l[3]));
        float e[4], s = 0.0f;
        #pragma unroll
        for (int o = 0; o < 4; ++o) { e[o] = fast_exp(l[o] - mx); s += e[o]; }
        float inv_s = __builtin_amdgcn_rcpf(s);
        float ls = __builtin_amdgcn_logf(s) * LN2;   // ln(s) via v_log_f32

        float4 ppi, plp, pxi;
        ppi.x = e[0] * inv_s; ppi.y = e[1] * inv_s;
        ppi.z = e[2] * inv_s; ppi.w = e[3] * inv_s;
        plp.x = (l[0] - mx) - ls; plp.y = (l[1] - mx) - ls;
        plp.z = (l[2] - mx) - ls; plp.w = (l[3] - mx) - ls;
        pxi.x = __builtin_amdgcn_rcpf(1.0f + fast_exp(-q[0]));
        pxi.y = __builtin_amdgcn_rcpf(1.0f + fast_exp(-q[1]));
        pxi.z = __builtin_amdgcn_rcpf(1.0f + fast_exp(-q[2]));
        pxi.w = __builtin_amdgcn_rcpf(1.0f + fast_exp(-q[3]));

        const size_t gi = ((size_t)b * NPAIR + p) * 4;
        *reinterpret_cast<float4*>(out + gi)           = ppi;
        *reinterpret_cast<float4*>(out + OFF + gi)     = plp;
        *reinterpret_cast<float4*>(out + 2 * OFF + gi) = pxi;
    }
}

extern "C" void kernel_launch(void* const* d_in, const int* in_sizes, int n_in,
                              void* d_out, int out_size, void* d_ws, size_t ws_size,
                              hipStream_t stream) {
    const float* nt  = (const float*)d_in[0];
    const float* W1  = (const float*)d_in[1];
    const float* b1  = (const float*)d_in[2];
    const float* g1  = (const float*)d_in[3];
    const float* be1 = (const float*)d_in[4];
    const float* W2  = (const float*)d_in[5];
    const float* b2  = (const float*)d_in[6];
    const float* g2  = (const float*)d_in[7];
    const float* be2 = (const float*)d_in[8];
    const float* Wpi = (const float*)d_in[9];
    const float* bpi = (const float*)d_in[10];
    const float* Wxi = (const float*)d_in[11];
    const float* bxi = (const float*)d_in[12];
    float* out = (float*)d_out;

    const int total = NPAIR * (BD / BCHUNK);   // 524,288 threads, 16 outputs each
    dim3 grid(total / 256), block(256);
    net_kernel<<<grid, block, 0, stream>>>(nt, W1, b1, g1, be1, W2, b2, g2, be2,
                                           Wpi, bpi, Wxi, bxi, out);
}